// Round 9
// baseline (41.015 us; speedup 1.0000x reference)
//
#include <hip/hip_runtime.h>
#include <hip/hip_bf16.h>
#include <hip/hip_fp16.h>

typedef __attribute__((ext_vector_type(8))) short bf16x8;
typedef __attribute__((ext_vector_type(4))) float f32x4;
typedef __attribute__((ext_vector_type(4))) int   i32x4;

#define O_TOTAL 8192
#define I_TOTAL 8192
#define NWAVES  8
#define NSS     16                                 // supersteps: 16 k-blocks each
#define ROW_I32 (I_TOTAL / 2)                      // 4096 int32 per weight row
#define NBLOCKS 256                                // 32-wide k-blocks per row

typedef __attribute__((address_space(1))) const void GASV;
typedef __attribute__((address_space(3))) void LASV;

static __device__ __forceinline__ short f2bf(float f) {
    union { __hip_bfloat16 b; short s; } u;
    u.b = __float2bfloat16(f);
    return u.s;
}

static __device__ __forceinline__ float bf2f(unsigned short s) {
    union { unsigned int u; float f; } v;
    v.u = ((unsigned int)s) << 16;
    return v.f;
}

// ---- kernel 0: x fp32 -> bf16 bits, once per launch ----
__global__ __launch_bounds__(256)
void xcvt_kernel(const float* __restrict__ x, short* __restrict__ xb)
{
    const int i = (blockIdx.x * 256 + threadIdx.x) * 4;   // 4 elems/thread
    f32x4 v = *(const f32x4*)(x + i);
    union { short s[4]; long long q; } p;
    p.s[0] = f2bf(v[0]); p.s[1] = f2bf(v[1]); p.s[2] = f2bf(v[2]); p.s[3] = f2bf(v[3]);
    *(long long*)(xb + i) = p.q;
}

// ---- kernel 1: main MFMA kernel — 1KB staged runs, x in registers ----
__global__ __launch_bounds__(512, 6)
void linq4_kernel(const short* __restrict__ xb,    // x as bf16 bits [16][8192]
                  const int* __restrict__ wq,
                  const void* __restrict__ wn,     // norm buffer, dtype sniffed at runtime
                  const float* __restrict__ bias,
                  float* __restrict__ out)
{
    const int tid  = threadIdx.x;
    const int w    = tid >> 6;             // wave 0..7
    const int lane = tid & 63;
    const int otile = blockIdx.x;          // 0..511 : 16 output rows each
    const int o0   = otile * 16;
    const int phase = (otile * 5) & (NSS - 1);   // per-block circular k-phase

    // ---- sniff the norm buffer's storage format ----
    const unsigned int* w32 = (const unsigned int*)wn;
    int cntLo = 0, cntHi = 0;
    #pragma unroll
    for (int i = 0; i < 16; ++i) {
        unsigned int ww = w32[i];
        unsigned int lo = ww & 0xFFFFu, hi = ww >> 16;
        if (lo >= 0x3980u && lo < 0x3F80u) cntLo++;
        if (hi >= 0x3C00u) cntHi++;
    }
    const int fmt = (cntLo >= 12) ? 1 : (cntHi >= 12 ? 0 : 2); // 0=f32 1=bf16 2=f16

    // ---- LDS ----
    __shared__ int   w_lds[2][4096];       // 2 x 16KB: [16 rows][256 int32 = 1KB]
    __shared__ float nlds[NBLOCKS];        // 1KB
    __shared__ float red[NWAVES][256];     // 8KB

    if (tid < NBLOCKS) {
        const int idx = otile * NBLOCKS + tid;
        float nf;
        if (fmt == 0)      nf = ((const float*)wn)[idx];
        else if (fmt == 1) nf = bf2f(((const unsigned short*)wn)[idx]);
        else               nf = __half2float(((const __half*)wn)[idx]);
        nlds[tid] = nf;
    }

    // ---- staging geometry: wave w stages rows 2w (instr0) and 2w+1 (instr1),
    //      1KB per row per superstep; global unit pre-swizzled u_g = lane ^ (r&7)
    //      (involution, permutes within 128B groups -> coalescing preserved)
    const int r0 = 2 * w, r1 = 2 * w + 1;
    const int ug0 = lane ^ (r0 & 7);
    const int ug1 = lane ^ (r1 & 7);
    const int* gw0 = wq + (size_t)(o0 + r0) * ROW_I32 + ug0 * 4;   // +Sp*256 int32
    const int* gw1 = wq + (size_t)(o0 + r1) * ROW_I32 + ug1 * 4;

    // ---- consume geometry: wave w owns k-blocks {2w, 2w+1} each superstep ----
    const int colc = lane & 15;            // B col / A row (m)
    const int kg   = lane >> 4;            // 0..3
    const int b0i  = 2 * w, b1i = 2 * w + 1;   // k-block-in-superstep
    // swizzled 16B-unit within the 1KB row: u' = (b*4+kg) ^ (col&7)
    const int ldsoff0 = colc * 256 + (((b0i * 4 + kg) ^ (colc & 7)) * 4);
    const int ldsoff1 = colc * 256 + (((b1i * 4 + kg) ^ (colc & 7)) * 4);
    const short* xrow = xb + (size_t)colc * I_TOTAL + kg * 8;      // + B*32

    f32x4 acc = {0.f, 0.f, 0.f, 0.f};

    bf16x8 xa_p0_0, xa_p0_1, xa_p1_0, xa_p1_1;   // x reg ring, parity 0/1

    // ---- prologue: stage superstep 0 (buf0) + x(0) (parity0) ----
    {
        const int Sp = phase;
        __builtin_amdgcn_global_load_lds((GASV*)(gw0 + (size_t)Sp * 256),
                                         (LASV*)(&w_lds[0][r0 * 256]), 16, 0, 0);
        __builtin_amdgcn_global_load_lds((GASV*)(gw1 + (size_t)Sp * 256),
                                         (LASV*)(&w_lds[0][r1 * 256]), 16, 0, 0);
        xa_p0_0 = *(const bf16x8*)(xrow + (size_t)(Sp * 16 + b0i) * 32);
        xa_p0_1 = *(const bf16x8*)(xrow + (size_t)(Sp * 16 + b1i) * 32);
    }

#define DO_STEP(T, CUR)                                                              \
    do {                                                                             \
        __syncthreads(); /* drains vmcnt+lgkm: stage T landed, buf !CUR free */      \
        const int Sp = ((T) + phase) & (NSS - 1);                                    \
        if ((T) + 1 < NSS) {                                                         \
            const int Spn = ((T) + 1 + phase) & (NSS - 1);                           \
            __builtin_amdgcn_global_load_lds((GASV*)(gw0 + (size_t)Spn * 256),       \
                                             (LASV*)(&w_lds[(CUR) ^ 1][r0 * 256]), 16, 0, 0); \
            __builtin_amdgcn_global_load_lds((GASV*)(gw1 + (size_t)Spn * 256),       \
                                             (LASV*)(&w_lds[(CUR) ^ 1][r1 * 256]), 16, 0, 0); \
            if ((CUR) == 0) {                                                        \
                xa_p1_0 = *(const bf16x8*)(xrow + (size_t)(Spn * 16 + b0i) * 32);    \
                xa_p1_1 = *(const bf16x8*)(xrow + (size_t)(Spn * 16 + b1i) * 32);    \
            } else {                                                                 \
                xa_p0_0 = *(const bf16x8*)(xrow + (size_t)(Spn * 16 + b0i) * 32);    \
                xa_p0_1 = *(const bf16x8*)(xrow + (size_t)(Spn * 16 + b1i) * 32);    \
            }                                                                        \
        }                                                                            \
        i32x4 pv0 = *(const i32x4*)(&w_lds[CUR][ldsoff0]);                           \
        i32x4 pv1 = *(const i32x4*)(&w_lds[CUR][ldsoff1]);                           \
        {                                                                            \
            const float nf = nlds[Sp * 16 + b0i];                                    \
            const float sc = nf * (2.0f / 15.0f);                                    \
            bf16x8 bfrag;                                                            \
            _Pragma("unroll")                                                        \
            for (int c = 0; c < 4; ++c) {                                            \
                int v = pv0[c];                                                      \
                bfrag[2*c]   = f2bf((float)(v & 15)        * sc - nf);               \
                bfrag[2*c+1] = f2bf((float)((v >> 4) & 15) * sc - nf);               \
            }                                                                        \
            acc = __builtin_amdgcn_mfma_f32_16x16x32_bf16(                           \
                      ((CUR) == 0 ? xa_p0_0 : xa_p1_0), bfrag, acc, 0, 0, 0);        \
        }                                                                            \
        {                                                                            \
            const float nf = nlds[Sp * 16 + b1i];                                    \
            const float sc = nf * (2.0f / 15.0f);                                    \
            bf16x8 bfrag;                                                            \
            _Pragma("unroll")                                                        \
            for (int c = 0; c < 4; ++c) {                                            \
                int v = pv1[c];                                                      \
                bfrag[2*c]   = f2bf((float)(v & 15)        * sc - nf);               \
                bfrag[2*c+1] = f2bf((float)((v >> 4) & 15) * sc - nf);               \
            }                                                                        \
            acc = __builtin_amdgcn_mfma_f32_16x16x32_bf16(                           \
                      ((CUR) == 0 ? xa_p0_1 : xa_p1_1), bfrag, acc, 0, 0, 0);        \
        }                                                                            \
    } while (0)

    #pragma unroll
    for (int t2 = 0; t2 < NSS / 2; ++t2) {
        DO_STEP(2 * t2,     0);
        DO_STEP(2 * t2 + 1, 1);
    }
#undef DO_STEP

    // ---- cross-wave K reduction ----
    __syncthreads();   // all consumption done before red reuse ordering
    *(f32x4*)&red[w][lane * 4] = acc;
    __syncthreads();

    if (tid < 256) {
        float s = 0.f;
        #pragma unroll
        for (int q = 0; q < NWAVES; ++q) s += red[q][tid];
        const int l = tid >> 2;            // original lane
        const int r = tid & 3;             // acc register index
        const int m  = ((l >> 4) << 2) + r;    // C row = (lane>>4)*4 + reg
        const int oc = o0 + (l & 15);          // C col = lane&15
        out[(size_t)m * O_TOTAL + oc] = s + bias[oc];
    }
}

extern "C" void kernel_launch(void* const* d_in, const int* in_sizes, int n_in,
                              void* d_out, int out_size, void* d_ws, size_t ws_size,
                              hipStream_t stream) {
    const float* x    = (const float*)d_in[0];
    const int*   wq   = (const int*)d_in[1];
    const void*  wn   = (const void*)d_in[2];   // dtype sniffed on device
    const float* bias = (const float*)d_in[3];
    float* out = (float*)d_out;
    short* xb  = (short*)d_ws;                  // 16*8192 bf16 = 256 KB scratch

    // stage 0: convert x to bf16
    hipLaunchKernelGGL(xcvt_kernel, dim3(16 * I_TOTAL / 4 / 256), dim3(256), 0, stream, x, xb);

    // stage 1: main kernel — 1KB staged runs, 16 supersteps, x in regs
    hipLaunchKernelGGL(linq4_kernel, dim3(O_TOTAL / 16), dim3(512), 0, stream,
                       (const short*)xb, wq, wn, bias, out);
}

// Round 10
// 40.463 us; speedup vs baseline: 1.0137x; 1.0137x over previous
//
#include <hip/hip_runtime.h>
#include <hip/hip_bf16.h>
#include <hip/hip_fp16.h>

typedef __attribute__((ext_vector_type(8))) short bf16x8;
typedef __attribute__((ext_vector_type(4))) float f32x4;
typedef __attribute__((ext_vector_type(4))) int   i32x4;

#define O_TOTAL 8192
#define I_TOTAL 8192
#define NWAVES  8
#define ROW_I32 4096       // int32 per weight row
#define NBLOCKS 256        // 32-wide k-blocks per row
#define NBATCH  4          // batches per wave, 8 k-blocks (256 k) each

static __device__ __forceinline__ short f2bf(float f) {
    union { __hip_bfloat16 b; short s; } u;
    u.b = __float2bfloat16(f);
    return u.s;
}

static __device__ __forceinline__ float bf2f(unsigned short s) {
    union { unsigned int u; float f; } v;
    v.u = ((unsigned int)s) << 16;
    return v.f;
}

// ---- kernel 0: x fp32 -> bf16 bits, once per launch ----
__global__ __launch_bounds__(256)
void xcvt_kernel(const float* __restrict__ x, short* __restrict__ xb)
{
    const int i = (blockIdx.x * 256 + threadIdx.x) * 4;
    f32x4 v = *(const f32x4*)(x + i);
    union { short s[4]; long long q; } p;
    p.s[0] = f2bf(v[0]); p.s[1] = f2bf(v[1]); p.s[2] = f2bf(v[2]); p.s[3] = f2bf(v[3]);
    *(long long*)(xb + i) = p.q;
}

// ---- kernel 1: wave-autonomous reg-staged MFMA kernel (no main-loop barriers) ----
__global__ __launch_bounds__(512, 4)
void linq4_kernel(const short* __restrict__ xb,    // x as bf16 bits [16][8192]
                  const int* __restrict__ wq,
                  const void* __restrict__ wn,     // norm buffer, dtype sniffed
                  const float* __restrict__ bias,
                  float* __restrict__ out)
{
    const int tid  = threadIdx.x;
    const int w    = tid >> 6;             // wave 0..7 (k-eighth: 1024 k)
    const int lane = tid & 63;
    const int otile = blockIdx.x;          // 0..511 : 16 output rows each
    const int o0   = otile * 16;
    const int ph   = (otile * 3) & 3;      // per-block batch phase (decorrelation)

    // ---- sniff the norm buffer's storage format ----
    const unsigned int* w32 = (const unsigned int*)wn;
    int cntLo = 0, cntHi = 0;
    #pragma unroll
    for (int i = 0; i < 16; ++i) {
        unsigned int ww = w32[i];
        unsigned int lo = ww & 0xFFFFu, hi = ww >> 16;
        if (lo >= 0x3980u && lo < 0x3F80u) cntLo++;
        if (hi >= 0x3C00u) cntHi++;
    }
    const int fmt = (cntLo >= 12) ? 1 : (cntHi >= 12 ? 0 : 2); // 0=f32 1=bf16 2=f16

    // ---- LDS: per-wave private 8KB W-batch + norms + reduction ----
    __shared__ int   wlds[NWAVES][2048];   // 8 x 8KB, wave-private
    __shared__ float nlds[NBLOCKS];        // 1KB
    __shared__ float red[NWAVES][256];     // 8KB

    if (tid < NBLOCKS) {
        const int idx = otile * NBLOCKS + tid;
        float nf;
        if (fmt == 0)      nf = ((const float*)wn)[idx];
        else if (fmt == 1) nf = bf2f(((const unsigned short*)wn)[idx]);
        else               nf = __half2float(((const __half*)wn)[idx]);
        nlds[tid] = nf;
    }
    __syncthreads();   // the ONLY pre-epilogue barrier: nlds visibility

    // ---- staging geometry: inst g covers rows {2g, 2g+1} x 512B (8 k-blocks) ----
    const int srow = lane >> 5;            // 0/1: which row of the pair
    const int su   = lane & 31;            // 16B unit within the 512B row-window
    // ---- consume geometry ----
    const int col  = lane & 15;            // B col / A row (m)
    const int kg   = lane >> 4;            // 0..3 k-subgroup

    char* wbase = (char*)&wlds[w][0];
    const short* xrow = xb + (size_t)col * I_TOTAL + kg * 8;

    f32x4 acc = {0.f, 0.f, 0.f, 0.f};

    i32x4  wreg[8];
    bf16x8 xreg[8];

    // prologue: load batch 0 weights into registers (512B contiguous per 32 lanes)
    {
        const int cw0 = w * 32 + ph * 8;
        #pragma unroll
        for (int g = 0; g < 8; ++g)
            wreg[g] = *(const i32x4*)(wq + (size_t)(o0 + 2*g + srow) * ROW_I32
                                         + cw0 * 16 + su * 4);
    }

    #pragma unroll
    for (int b = 0; b < NBATCH; ++b) {
        const int pb  = (b + ph) & 3;
        const int cw0 = w * 32 + pb * 8;

        // x loads for this batch FIRST (so the wreg-wait at ds_write doesn't drain them)
        #pragma unroll
        for (int m = 0; m < 8; ++m)
            xreg[m] = *(const bf16x8*)(xrow + (size_t)(cw0 + m) * 32);
        __builtin_amdgcn_sched_barrier(0);   // pin: x issued before ds_write block

        // ds_write current W batch, XOR-swizzled (conflict-free b128 on read)
        #pragma unroll
        for (int g = 0; g < 8; ++g) {
            const int row = 2*g + srow;
            const int u2  = su ^ (row & 7);
            *(i32x4*)(wbase + row * 512 + u2 * 16) = wreg[g];
        }

        // issue next batch W loads (stay in flight across the whole consume phase)
        if (b + 1 < NBATCH) {
            const int cwn = w * 32 + (((b + 1 + ph) & 3) * 8);
            #pragma unroll
            for (int g = 0; g < 8; ++g)
                wreg[g] = *(const i32x4*)(wq + (size_t)(o0 + 2*g + srow) * ROW_I32
                                             + cwn * 16 + su * 4);
        }
        __builtin_amdgcn_sched_barrier(0);   // pin: prefetch issued before consume

        // consume 8 k-blocks: ds_read + dequant + MFMA (wave-local, no sync)
        #pragma unroll
        for (int m = 0; m < 8; ++m) {
            const int j2 = (m * 4 + kg) ^ (col & 7);
            i32x4 pv = *(const i32x4*)(wbase + col * 512 + j2 * 16);
            const float nf = nlds[w * 32 + pb * 8 + m];
            const float sc = nf * (2.0f / 15.0f);
            bf16x8 bfrag;
            #pragma unroll
            for (int c = 0; c < 4; ++c) {
                int v = pv[c];
                bfrag[2*c]   = f2bf((float)(v & 15)        * sc - nf);
                bfrag[2*c+1] = f2bf((float)((v >> 4) & 15) * sc - nf);
            }
            acc = __builtin_amdgcn_mfma_f32_16x16x32_bf16(xreg[m], bfrag, acc, 0, 0, 0);
        }
    }

    // ---- cross-wave K reduction (the only other barriers) ----
    *(f32x4*)&red[w][lane * 4] = acc;
    __syncthreads();

    if (tid < 256) {
        float s = 0.f;
        #pragma unroll
        for (int q = 0; q < NWAVES; ++q) s += red[q][tid];
        const int l = tid >> 2;            // original lane
        const int r = tid & 3;             // acc register index
        const int m  = ((l >> 4) << 2) + r;    // C row = (lane>>4)*4 + reg
        const int oc = o0 + (l & 15);          // C col = lane&15
        out[(size_t)m * O_TOTAL + oc] = s + bias[oc];
    }
}

extern "C" void kernel_launch(void* const* d_in, const int* in_sizes, int n_in,
                              void* d_out, int out_size, void* d_ws, size_t ws_size,
                              hipStream_t stream) {
    const float* x    = (const float*)d_in[0];
    const int*   wq   = (const int*)d_in[1];
    const void*  wn   = (const void*)d_in[2];   // dtype sniffed on device
    const float* bias = (const float*)d_in[3];
    float* out = (float*)d_out;
    short* xb  = (short*)d_ws;                  // 16*8192 bf16 = 256 KB scratch

    // stage 0: convert x to bf16
    hipLaunchKernelGGL(xcvt_kernel, dim3(16 * I_TOTAL / 4 / 256), dim3(256), 0, stream, x, xb);

    // stage 1: wave-autonomous main kernel
    hipLaunchKernelGGL(linq4_kernel, dim3(O_TOTAL / 16), dim3(512), 0, stream,
                       (const short*)xb, wq, wn, bias, out);
}